// Round 1
// baseline (9783.086 us; speedup 1.0000x reference)
//
#include <hip/hip_runtime.h>
#include <math.h>

#define N 64
#define LDSP 65          // +1 pad: 65 % 32 == 1 -> conflict-free row AND col access
#define SWEEPS 10
#define EPSV 1e-3
#define MAXEIG 1000.0

// One 64-thread wave per 64x64 symmetric matrix.
// Two-sided cyclic Jacobi (round-robin tournament ordering), A in LDS,
// eigenvector matrix V accumulated in registers (lane owns column `lane`),
// fp64 Rayleigh-quotient eigenvalue refinement, then V diag(log(clip(w))) V^T.
__global__ __launch_bounds__(64)
void spd_log_kernel(const float* __restrict__ x, float* __restrict__ out) {
    __shared__ float As[N][LDSP];
    __shared__ float carr[N / 2];
    __shared__ float sarr[N / 2];
    __shared__ float farr[N];

    const int lane = threadIdx.x;
    const size_t mat = blockIdx.x;
    const float* __restrict__ xm = x + mat * (size_t)(N * N);
    float* __restrict__ om = out + mat * (size_t)(N * N);

    // Load A: lane = column index, coalesced global reads.
    for (int r2 = 0; r2 < N; ++r2)
        As[r2][lane] = xm[r2 * N + lane];

    // V = I, lane holds column `lane`: v[k] = V[k][lane]
    float v[N];
#pragma unroll
    for (int k = 0; k < N; ++k) v[k] = (k == lane) ? 1.0f : 0.0f;

    __syncthreads();

    for (int sweep = 0; sweep < SWEEPS; ++sweep) {
        for (int r = 0; r < N - 1; ++r) {
            // Tournament schedule round r: arr[0]=0, arr[i]=1+((i-1+r)%63),
            // pair k = (arr[k], arr[63-k]) for k=0..31.
            if (lane < N / 2) {
                const int k = lane;
                const int p = (k == 0) ? 0 : 1 + (k - 1 + r) % 63;
                const int q = 1 + (62 - k + r) % 63;
                const float app = As[p][p];
                const float aqq = As[q][q];
                const float apq = As[p][q];
                float c = 1.0f, s = 0.0f;
                if (apq != 0.0f) {
                    const float tau = (aqq - app) / (2.0f * apq);
                    const float at = fabsf(tau);
                    float t = 1.0f / (at + sqrtf(1.0f + at * at));
                    t = copysignf(t, tau);
                    c = 1.0f / sqrtf(1.0f + t * t);
                    s = t * c;
                }
                carr[k] = c;
                sarr[k] = s;
            }
            __syncthreads();

            // Row phase: rows p,q mix; lane handles column `lane`.
            // new_row_p = c*row_p - s*row_q ; new_row_q = s*row_p + c*row_q
#pragma unroll
            for (int i = 0; i < N / 2; ++i) {
                const int p = (i == 0) ? 0 : 1 + (i - 1 + r) % 63;
                const int q = 1 + (62 - i + r) % 63;
                const float c = carr[i], s = sarr[i];
                const float rp = As[p][lane], rq = As[q][lane];
                As[p][lane] = c * rp - s * rq;
                As[q][lane] = s * rp + c * rq;
            }
            __syncthreads();

            // Column phase: cols p,q mix; lane handles row `lane`.
#pragma unroll
            for (int i = 0; i < N / 2; ++i) {
                const int p = (i == 0) ? 0 : 1 + (i - 1 + r) % 63;
                const int q = 1 + (62 - i + r) % 63;
                const float c = carr[i], s = sarr[i];
                const float cp = As[lane][p], cq = As[lane][q];
                As[lane][p] = c * cp - s * cq;
                As[lane][q] = s * cp + c * cq;
            }

            // V column rotation in registers (wave-level shuffles, no barrier needed).
            {
                const int pos = (lane == 0) ? 0 : 1 + ((lane - 1 - r) % 63 + 63) % 63;
                const int k = min(pos, 63 - pos);
                const int ppos = 63 - pos;
                const int partner = (ppos == 0) ? 0 : 1 + (ppos - 1 + r) % 63;
                const float cc = carr[k];
                const float ss = sarr[k];
                const float sg = (pos < 32) ? -ss : ss;  // p-side: c*v - s*pv ; q-side: c*v + s*pv
#pragma unroll
                for (int kk = 0; kk < N; ++kk) {
                    const float pv = __shfl(v[kk], partner);
                    v[kk] = cc * v[kk] + sg * pv;
                }
            }
            __syncthreads();
        }
    }

    // Dump V into As (A no longer needed): As[k][lane] = V[k][lane]
#pragma unroll
    for (int k = 0; k < N; ++k) As[k][lane] = v[k];

    // Rayleigh-quotient refinement in fp64 against the ORIGINAL input:
    // w = v^T X v / v^T v. Kills log-amplified eigenvalue error near eps.
    {
        double nrm = 0.0;
#pragma unroll
        for (int k = 0; k < N; ++k) nrm += (double)v[k] * (double)v[k];
        double acc = 0.0;
        for (int rr = 0; rr < N; ++rr) {
            double inner = 0.0;
#pragma unroll
            for (int c = 0; c < N; ++c)
                inner += (double)xm[rr * N + c] * (double)v[c];
            acc += (double)v[rr] * inner;
        }
        double wv = acc / nrm;
        wv = fmin(fmax(wv, EPSV), MAXEIG);
        farr[lane] = (float)log(wv);
    }
    __syncthreads();

    // Reconstruct: Out[rr][lane] = sum_j V[rr][j] * f_j * V[lane][j]
    float rowf[N];
#pragma unroll
    for (int j = 0; j < N; ++j) rowf[j] = As[lane][j] * farr[j];

    for (int rr = 0; rr < N; ++rr) {
        float acc = 0.0f;
#pragma unroll
        for (int j = 0; j < N; ++j) acc += As[rr][j] * rowf[j];
        om[rr * N + lane] = acc;
    }
}

extern "C" void kernel_launch(void* const* d_in, const int* in_sizes, int n_in,
                              void* d_out, int out_size, void* d_ws, size_t ws_size,
                              hipStream_t stream) {
    const float* x = (const float*)d_in[0];
    float* out = (float*)d_out;
    const int nmat = in_sizes[0] / (N * N);
    spd_log_kernel<<<dim3(nmat), dim3(64), 0, stream>>>(x, out);
}

// Round 2
// 8223.061 us; speedup vs baseline: 1.1897x; 1.1897x over previous
//
#include <hip/hip_runtime.h>
#include <math.h>

#define N 64
#define LDSP 65          // +1 pad: 65 % 32 == 1 -> conflict-free row AND col access
#define SWEEPS 10
#define EPSV 1e-3
#define MAXEIG 1000.0

// One 64-thread wave per 64x64 symmetric matrix.
// Two-sided cyclic Jacobi (round-robin tournament ordering), A in LDS,
// eigenvector matrix V accumulated in registers (lane owns column `lane`),
// fp64 Rayleigh-quotient eigenvalue refinement, then V diag(log(clip(w))) V^T.
//
// __launch_bounds__(64, 2): min 2 waves/EU -> VGPR cap 256. Round-1 build
// (default bounds) allocated only 80 VGPRs and spilled v[64] to scratch:
// 40 GB of HBM writes, kernel was 100% spill-traffic-bound.
__global__ __launch_bounds__(64, 2)
void spd_log_kernel(const float* __restrict__ x, float* __restrict__ out) {
    __shared__ float As[N][LDSP];
    __shared__ float carr[N / 2];
    __shared__ float sarr[N / 2];
    __shared__ float farr[N];

    const int lane = threadIdx.x;
    const size_t mat = blockIdx.x;
    const float* __restrict__ xm = x + mat * (size_t)(N * N);
    float* __restrict__ om = out + mat * (size_t)(N * N);

    // Load A: lane = column index, coalesced global reads.
    for (int r2 = 0; r2 < N; ++r2)
        As[r2][lane] = xm[r2 * N + lane];

    // V = I, lane holds column `lane`: v[k] = V[k][lane]
    float v[N];
#pragma unroll
    for (int k = 0; k < N; ++k) v[k] = (k == lane) ? 1.0f : 0.0f;

    __syncthreads();

    for (int sweep = 0; sweep < SWEEPS; ++sweep) {
        for (int r = 0; r < N - 1; ++r) {
            // Tournament schedule round r: arr[0]=0, arr[i]=1+((i-1+r)%63),
            // pair k = (arr[k], arr[63-k]) for k=0..31.
            if (lane < N / 2) {
                const int k = lane;
                const int p = (k == 0) ? 0 : 1 + (k - 1 + r) % 63;
                const int q = 1 + (62 - k + r) % 63;
                const float app = As[p][p];
                const float aqq = As[q][q];
                const float apq = As[p][q];
                float c = 1.0f, s = 0.0f;
                if (apq != 0.0f) {
                    const float tau = (aqq - app) / (2.0f * apq);
                    const float at = fabsf(tau);
                    float t = 1.0f / (at + sqrtf(1.0f + at * at));
                    t = copysignf(t, tau);
                    c = 1.0f / sqrtf(1.0f + t * t);
                    s = t * c;
                }
                carr[k] = c;
                sarr[k] = s;
            }
            __syncthreads();

            // Row phase: rows p,q mix; lane handles column `lane`.
#pragma unroll
            for (int i = 0; i < N / 2; ++i) {
                const int p = (i == 0) ? 0 : 1 + (i - 1 + r) % 63;
                const int q = 1 + (62 - i + r) % 63;
                const float c = carr[i], s = sarr[i];
                const float rp = As[p][lane], rq = As[q][lane];
                As[p][lane] = c * rp - s * rq;
                As[q][lane] = s * rp + c * rq;
            }
            __syncthreads();

            // Column phase: cols p,q mix; lane handles row `lane`.
#pragma unroll
            for (int i = 0; i < N / 2; ++i) {
                const int p = (i == 0) ? 0 : 1 + (i - 1 + r) % 63;
                const int q = 1 + (62 - i + r) % 63;
                const float c = carr[i], s = sarr[i];
                const float cp = As[lane][p], cq = As[lane][q];
                As[lane][p] = c * cp - s * cq;
                As[lane][q] = s * cp + c * cq;
            }

            // V column rotation in registers (wave-level shuffles, no barrier).
            {
                const int pos = (lane == 0) ? 0 : 1 + ((lane - 1 - r) % 63 + 63) % 63;
                const int k = min(pos, 63 - pos);
                const int ppos = 63 - pos;
                const int partner = (ppos == 0) ? 0 : 1 + (ppos - 1 + r) % 63;
                const float cc = carr[k];
                const float ss = sarr[k];
                const float sg = (pos < 32) ? -ss : ss;  // p-side: c*v - s*pv ; q-side: c*v + s*pv
#pragma unroll
                for (int kk = 0; kk < N; ++kk) {
                    const float pv = __shfl(v[kk], partner);
                    v[kk] = cc * v[kk] + sg * pv;
                }
            }
            __syncthreads();
        }
    }

    // Rayleigh-quotient refinement in fp64 against the ORIGINAL input:
    // w = v^T X v / v^T v. Kills log-amplified eigenvalue error near eps.
    {
        double nrm = 0.0;
#pragma unroll
        for (int k = 0; k < N; ++k) nrm += (double)v[k] * (double)v[k];
        double acc = 0.0;
        for (int rr = 0; rr < N; ++rr) {
            double inner = 0.0;
#pragma unroll
            for (int c = 0; c < N; ++c)
                inner += (double)xm[rr * N + c] * (double)v[c];
            acc += (double)v[rr] * inner;
        }
        double wv = acc / nrm;
        wv = fmin(fmax(wv, EPSV), MAXEIG);
        farr[lane] = (float)log(wv);
    }

    __syncthreads();  // all lanes done reading As as A
    // Dump V into As (A no longer needed): As[k][lane] = V[k][lane]
#pragma unroll
    for (int k = 0; k < N; ++k) As[k][lane] = v[k];
    __syncthreads();

    // Reconstruct: Out[rr][lane] = sum_j V[rr][j] * f_j * V[lane][j]
    // Reuse v[] as the f-scaled row of V (cuts peak VGPR pressure).
#pragma unroll
    for (int j = 0; j < N; ++j) v[j] = As[lane][j] * farr[j];

    for (int rr = 0; rr < N; ++rr) {
        float acc = 0.0f;
#pragma unroll
        for (int j = 0; j < N; ++j) acc += As[rr][j] * v[j];
        om[rr * N + lane] = acc;
    }
}

extern "C" void kernel_launch(void* const* d_in, const int* in_sizes, int n_in,
                              void* d_out, int out_size, void* d_ws, size_t ws_size,
                              hipStream_t stream) {
    const float* x = (const float*)d_in[0];
    float* out = (float*)d_out;
    const int nmat = in_sizes[0] / (N * N);
    spd_log_kernel<<<dim3(nmat), dim3(64), 0, stream>>>(x, out);
}